// Round 1
// 3081.786 us; speedup vs baseline: 1.0771x; 1.0771x over previous
//
#include <hip/hip_runtime.h>
#include <math.h>

typedef __attribute__((ext_vector_type(8))) short short8;
typedef __attribute__((ext_vector_type(4))) float float4v;
typedef unsigned short ushort_t;
typedef unsigned char uchar_t;

#define S_LEN 512
#define BATCH 128
#define DMODEL 512
#define HIDDEN 256
#define NTAGS 32
#define MROWS (S_LEN*BATCH)
#define CHUNK 128                 // sequence steps per pre-band
#define EMB_SCALE 22.62741699796952f

__device__ __forceinline__ float bf2f(ushort_t u){
  union { unsigned int i; float f; } v; v.i = ((unsigned int)u)<<16; return v.f;
}
__device__ __forceinline__ ushort_t f2bf(float f){
  union { float f; unsigned int i; } v; v.f = f;
  unsigned int x = v.i;
  x += 0x7fffu + ((x>>16)&1u);
  return (ushort_t)(x>>16);
}
// float -> OCP e4m3fn, RNE, saturate to 448
__device__ __forceinline__ uchar_t f2fp8(float f){
  float a = fabsf(f);
  unsigned int s = (__float_as_uint(f) >> 24) & 0x80u;
  if (a >= 448.f) return (uchar_t)(s | 0x7Eu);
  if (a < 0.015625f){                         // subnormal: m = round(a*512)
    unsigned int q = (unsigned int)__float2int_rn(a * 512.0f);
    return (uchar_t)(s | q);
  }
  unsigned int x = __float_as_uint(a);
  x += 0x7FFFFu + ((x >> 20) & 1u);           // RNE into 3-bit mantissa
  int e = (int)((x >> 23) & 0xFFu) - 127;
  unsigned int m = (x >> 20) & 7u;
  if (e > 8) return (uchar_t)(s | 0x7Eu);
  return (uchar_t)(s | ((unsigned)(e + 7) << 3) | m);
}
__device__ __forceinline__ float sigm(float x){ return 1.0f/(1.0f+__expf(-x)); }
__device__ __forceinline__ float tanh_f(float x){ return 2.0f/(1.0f+__expf(-2.0f*x)) - 1.0f; }

#define MFMA(a,b,c) __builtin_amdgcn_mfma_f32_16x16x32_bf16(a,b,c,0,0,0)
#define MFMA8(a,b,c) __builtin_amdgcn_mfma_f32_16x16x32_fp8_fp8(a,b,c,0,0,0)

// ---------------- elementwise helpers ----------------
__global__ void k_cvt_bf16(const float* __restrict__ s, ushort_t* __restrict__ d, int n){
  int i = blockIdx.x*blockDim.x + threadIdx.x;
  if(i<n) d[i] = f2bf(s[i]);
}
__global__ void k_cvt_fp8(const float* __restrict__ s, uchar_t* __restrict__ d, int n){
  int i = blockIdx.x*blockDim.x + threadIdx.x;
  if(i<n) d[i] = f2fp8(s[i]);
}
__global__ void k_biassum(const float* __restrict__ a, const float* __restrict__ b,
                          float* __restrict__ o, int n){
  int i = blockIdx.x*blockDim.x + threadIdx.x;
  if(i<n) o[i] = a[i]+b[i];
}

// ---------------- embedding: x[s,b,:] = emb[src[s,b],:]*sqrt(D)  (bf16 out) ----
__global__ __launch_bounds__(64) void k_embed(const int* __restrict__ src,
                                              const float* __restrict__ emb,
                                              ushort_t* __restrict__ x){
  int row = blockIdx.x;            // 0..65535  (= s*BATCH+b)
  int t = threadIdx.x;             // 64 threads, 8 elems each
  int tok = src[row];
  const float4v* e = (const float4v*)(emb + (size_t)tok*DMODEL + t*8);
  float4v a = e[0], b = e[1];
  short8 o;
  o[0]=(short)f2bf(a[0]*EMB_SCALE); o[1]=(short)f2bf(a[1]*EMB_SCALE);
  o[2]=(short)f2bf(a[2]*EMB_SCALE); o[3]=(short)f2bf(a[3]*EMB_SCALE);
  o[4]=(short)f2bf(b[0]*EMB_SCALE); o[5]=(short)f2bf(b[1]*EMB_SCALE);
  o[6]=(short)f2bf(b[2]*EMB_SCALE); o[7]=(short)f2bf(b[3]*EMB_SCALE);
  *(short8*)(x + (size_t)row*DMODEL + t*8) = o;
}

// ---------------- band pre-GEMM: C[Mband,N] = A[Mband,512] @ W[N,512]^T + bias -
// perm!=0: write gate-interleaved layout col' = (unit<<2)|gate (unit=col&255,
// gate=col>>8) so the scan kernel reads 4 gates of one unit as one ushort4.
__global__ __launch_bounds__(256) void k_gemm_pre(const ushort_t* __restrict__ A,
                                                  const ushort_t* __restrict__ W,
                                                  const float* __restrict__ bias,
                                                  ushort_t* __restrict__ C, int N,
                                                  int perm){
  __shared__ __align__(16) ushort_t As[64][40];   // +8 pad: 2-way banks only
  __shared__ __align__(16) ushort_t Bs[64][40];
  const int K = 512;
  int bn = blockIdx.x;             // N/64 tiles
  int bm = blockIdx.y;             // Mband/64 tiles
  int tid = threadIdx.x;
  int lane = tid & 63, wave = tid >> 6;
  int wm = wave >> 1, wn = wave & 1;        // 32x32 quadrant per wave
  int srow = tid >> 2, scg = tid & 3;       // staging: row, 8-elem group
  float4v acc[2][2] = {};
  const ushort_t* Ag = A + ((size_t)(bm*64 + srow))*K + scg*8;
  const ushort_t* Wg = W + ((size_t)(bn*64 + srow))*K + scg*8;
  int r = lane & 15;
  int kq = (lane >> 4) * 8;
  for(int kt=0; kt<K/32; ++kt){
    *(short8*)&As[srow][scg*8] = *(const short8*)(Ag + kt*32);
    *(short8*)&Bs[srow][scg*8] = *(const short8*)(Wg + kt*32);
    __syncthreads();
    short8 a0 = *(const short8*)&As[wm*32 +      r][kq];
    short8 a1 = *(const short8*)&As[wm*32 + 16 + r][kq];
    short8 b0 = *(const short8*)&Bs[wn*32 +      r][kq];
    short8 b1 = *(const short8*)&Bs[wn*32 + 16 + r][kq];
    acc[0][0] = MFMA(a0,b0,acc[0][0]);
    acc[0][1] = MFMA(a0,b1,acc[0][1]);
    acc[1][0] = MFMA(a1,b0,acc[1][0]);
    acc[1][1] = MFMA(a1,b1,acc[1][1]);
    __syncthreads();
  }
  int r0 = (lane>>4)*4, cc = lane & 15;
  for(int mt=0;mt<2;++mt) for(int nt=0;nt<2;++nt){
    int col = bn*64 + wn*32 + nt*16 + cc;
    float bv = bias[col];
    int colp = perm ? (((col & 255) << 2) | (col >> 8)) : col;
    for(int j=0;j<4;++j){
      int row = bm*64 + wm*32 + mt*16 + r0 + j;
      C[(size_t)row*N + colp] = f2bf(acc[mt][nt][j] + bv);
    }
  }
}

// ---------------- per-batch bidirectional LSTM scan over one CHUNK ------------
// grid = 256 blocks x 512 threads: bid = d*128 + b. ONE batch element per
// block -> every CU busy; recurrence is batch-independent so no cross-block
// traffic. Per step each block multiplies full Whh[1024x256] by h[b] (MFMA
// M-rows 1/16 used -- redundant but per-CU MFMA cost is invariant to
// batches/block, so minimum batches/block maximizes CU count).
// Wave w owns units [w*32,+32), all 4 gates: 8 acc tiles (g,uh), 64 MFMA/step,
// fp8 weights resident in 128 VGPRs/lane. Cell math only in lanes hi==0
// (acc row 0 = batch b). hbuf rows 1..15 are zeroed once; only row 0 is live.
__global__ __launch_bounds__(512,1) void k_scan3(
    const ushort_t* __restrict__ preF,   // [CHUNK*B][1024] gate-interleaved dir0
    const ushort_t* __restrict__ preB,   // same, dir1 band (band rows = seq high->low)
    const uchar_t* __restrict__ Wq,      // [2,1024,256] fp8 (this layer)
    uchar_t* __restrict__ hstate,        // [2,128,256] fp8 carry between chunks
    float* __restrict__ cstate,          // [2,128,256] f32
    ushort_t* __restrict__ xout,         // [S*B,512] bf16
    int t0){
  __shared__ __align__(8) uchar_t hbuf[2][16][264];   // 8448 B; rows 1..15 = 0
  int bid = blockIdx.x;
  int d = bid >> 7, b = bid & 127;
  int tid = threadIdx.x;
  int w = tid >> 6, lane = tid & 63;
  int lo = lane & 15, hi = lane >> 4;
  int u0 = w*32;                           // wave's unit base [0,256)

  // zero hbuf, then load initial h row
  for(int i = tid*4; i < 2*16*264; i += 512*4)
    *(unsigned int*)((uchar_t*)hbuf + i) = 0u;
  __syncthreads();
  if(tid < 64)
    *(unsigned int*)&hbuf[0][0][tid*4] =
      *(const unsigned int*)(hstate + ((size_t)d*BATCH + b)*HIDDEN + tid*4);

  // fp8 weights -> 128 VGPRs/lane: wq[g][uh][kk]
  long long wq[4][2][8];
  const uchar_t* Wd = Wq + (size_t)d*1024*HIDDEN;
  #pragma unroll
  for(int g=0; g<4; ++g)
    #pragma unroll
    for(int uh=0; uh<2; ++uh)
      #pragma unroll
      for(int kk=0; kk<8; ++kk)
        wq[g][uh][kk] = *(const long long*)
          (Wd + (size_t)(g*256 + u0 + uh*16 + lo)*HIDDEN + kk*32 + hi*8);

  float c[2];
  #pragma unroll
  for(int uh=0; uh<2; ++uh)
    c[uh] = cstate[((size_t)d*BATCH + b)*HIDDEN + u0 + uh*16 + lo];

  const ushort_t* pp = (d ? preB : preF) + (size_t)b*1024;
  ushort4 pc[2], pn[2];
  {
    int br = d ? (CHUNK-1) : 0;
    if(hi==0){
      #pragma unroll
      for(int uh=0; uh<2; ++uh)
        pc[uh] = *(const ushort4*)(pp + (size_t)br*BATCH*1024 + (u0+uh*16+lo)*4);
    }
  }
  __syncthreads();

  for(int sb=0; sb<CHUNK; ++sb){
    int p = sb & 1;
    // prefetch next step's pre (independent of recurrence)
    int sb2 = (sb+1 < CHUNK) ? sb+1 : sb;
    int br2 = d ? (CHUNK-1-sb2) : sb2;
    if(hi==0){
      #pragma unroll
      for(int uh=0; uh<2; ++uh)
        pn[uh] = *(const ushort4*)(pp + (size_t)br2*BATCH*1024 + (u0+uh*16+lo)*4);
    }

    float4v acc[4][2] = {};
    #pragma unroll
    for(int kk=0; kk<8; ++kk){
      long long a8 = *(const long long*)&hbuf[p][lo][kk*32 + hi*8];
      #pragma unroll
      for(int g=0; g<4; ++g){
        acc[g][0] = MFMA8(a8, wq[g][0][kk], acc[g][0]);
        acc[g][1] = MFMA8(a8, wq[g][1][kk], acc[g][1]);
      }
    }

    int s = t0 + sb;
    int s_eff = d ? (S_LEN-1-s) : s;
    if(hi==0){
      #pragma unroll
      for(int uh=0; uh<2; ++uh){
        float gi = acc[0][uh][0] + bf2f(pc[uh].x);
        float gf = acc[1][uh][0] + bf2f(pc[uh].y);
        float gg = acc[2][uh][0] + bf2f(pc[uh].z);
        float go = acc[3][uh][0] + bf2f(pc[uh].w);
        float cn = sigm(gf)*c[uh] + sigm(gi)*tanh_f(gg);
        float hn = sigm(go)*tanh_f(cn);
        c[uh] = cn;
        int u = u0 + uh*16 + lo;
        hbuf[p^1][0][u] = f2fp8(hn);
        xout[((size_t)s_eff*BATCH + b)*DMODEL + d*HIDDEN + u] = f2bf(hn);
      }
    }
    __syncthreads();
    #pragma unroll
    for(int uh=0; uh<2; ++uh) pc[uh] = pn[uh];
  }

  // write back h (CHUNK even -> final h in hbuf[0]) and c
  if(tid < 64)
    *(unsigned int*)(hstate + ((size_t)d*BATCH + b)*HIDDEN + tid*4) =
      *(const unsigned int*)&hbuf[0][0][tid*4];
  if(hi==0){
    #pragma unroll
    for(int uh=0; uh<2; ++uh)
      cstate[((size_t)d*BATCH + b)*HIDDEN + u0 + uh*16 + lo] = c[uh];
  }
}

// ---------------- logits: [M,32] = x[M,512] @ W_lin^T + b_lin  (f32 out) ------
__global__ __launch_bounds__(128) void k_logits(const ushort_t* __restrict__ x,
                                                const ushort_t* __restrict__ Wl,
                                                const float* __restrict__ bl,
                                                float* __restrict__ logits){
  __shared__ ushort_t xr[16][512];
  __shared__ ushort_t wl[32][520];   // pad -> 4-way max
  int tid = threadIdx.x;
  int base = blockIdx.x * 16;
  for(int i=tid; i<16*64; i+=128){
    int row = i >> 6, cg = i & 63;
    *(short8*)&xr[row][cg*8] = *(const short8*)(x + (size_t)(base+row)*DMODEL + cg*8);
  }
  for(int i=tid; i<32*64; i+=128){
    int row = i >> 6, cg = i & 63;
    *(short8*)&wl[row][cg*8] = *(const short8*)(Wl + (size_t)row*DMODEL + cg*8);
  }
  __syncthreads();
  int rr = tid >> 5, t = tid & 31;
  float bv = bl[t];
  for(int p=0;p<4;++p){
    int row = p*4 + rr;
    float sum = 0.f;
    for(int k8=0;k8<64;++k8){
      short8 xv = *(const short8*)&xr[row][k8*8];
      short8 wv = *(const short8*)&wl[t][k8*8];
      #pragma unroll
      for(int j=0;j<8;++j)
        sum += bf2f((ushort_t)xv[j]) * bf2f((ushort_t)wv[j]);
    }
    logits[((size_t)(base+row))*NTAGS + t] = sum + bv;
  }
}

// ---------------- CRF partition: per-batch alpha recurrence ------------------
// Scaled exp-domain formulation: a[t] = exp(alpha[t] - M).  Per step:
//   a_new[t] = (sum_j a[j]*expT[j][t]) * exp(e[t])
// expT held in 32 VGPRs/lane (computed once); only ONE transcendental per
// step on the critical path, and its input (emission) is prefetched 2 steps
// ahead.  All sums are of positive terms (no cancellation).  Exact power-of-2
// rescale keeps a in range; triggered by a cheap wave-uniform __any/__all
// check.  Lanes 32-63 mirror lanes 0-31 (uniform wave ops, no divergence).
__global__ __launch_bounds__(64) void k_crf(const float* __restrict__ logits,
                                            const float* __restrict__ trans,
                                            float* __restrict__ logz){
  __shared__ __align__(16) float sh[32];
  int b = blockIdx.x, tid = threadIdx.x;
  int t = tid & 31;                       // lanes 32-63 mirror 0-31

  // per-lane column of exp(T): eT[j] = exp(trans[j][t])
  float eT[32];
  #pragma unroll
  for(int j=0;j<32;++j) eT[j] = __expf(trans[j*NTAGS + t]);

  // init: alpha0 = logits[0,b,:]; a = exp(alpha0 - m0), M = m0
  float al0 = logits[(size_t)b*NTAGS + t];
  float m0 = al0;
  #pragma unroll
  for(int o=1;o<32;o<<=1) m0 = fmaxf(m0, __shfl_xor(m0, o));
  float Mf = m0;
  float a = __expf(al0 - m0);

  const size_t stp = (size_t)BATCH*NTAGS;
  const float* ebase = logits + (size_t)b*NTAGS + t;
  float eCur = ebase[stp*1];              // emission for step 1
  float eNxt = ebase[stp*2];              // emission for step 2
  const float* eptr = ebase + stp*3;      // prefetch pointer (step i+2 at i=1)

  for(int i=1;i<S_LEN;++i){
    float expE = __expf(eCur);            // input was prefetched 2 steps ago
    if(tid < 32) sh[t] = a;
    __syncthreads();
    // prefetch emission for step i+2 (independent of recurrence)
    float eP = 0.f;
    if(i+2 < S_LEN) eP = *eptr;
    eptr += stp;
    // s_t = sum_j a[j] * expT[j][t] — 4 independent FMA chains
    float s0=0.f, s1=0.f, s2=0.f, s3=0.f;
    const float4v* s4 = (const float4v*)sh;
    #pragma unroll
    for(int q=0;q<8;++q){
      float4v v = s4[q];
      s0 = __fmaf_rn(v[0], eT[q*4+0], s0);
      s1 = __fmaf_rn(v[1], eT[q*4+1], s1);
      s2 = __fmaf_rn(v[2], eT[q*4+2], s2);
      s3 = __fmaf_rn(v[3], eT[q*4+3], s3);
    }
    a = ((s0+s1)+(s2+s3)) * expE;
    eCur = eNxt; eNxt = eP;
    // exact power-of-2 renorm when out of range (wave-uniform branch)
    if(__any(a > 1.1529215e18f) || __all(a < 9.0949470e-13f)){   // 2^60 / 2^-40
      float m = a;
      #pragma unroll
      for(int o=1;o<32;o<<=1) m = fmaxf(m, __shfl_xor(m, o));
      int e2 = (int)((__float_as_uint(m)>>23)&255u) - 127;
      float scl = __uint_as_float((unsigned)(127 - e2) << 23);   // 2^-e2 exact
      a *= scl;
      Mf += (float)e2 * 0.69314718055994531f;
    }
    __syncthreads();
  }
  // logz = M + log(sum_t a)
  float sum = a;
  #pragma unroll
  for(int o=1;o<32;o<<=1) sum += __shfl_xor(sum, o);
  if(tid==0) logz[b] = Mf + __logf(sum);
}

// ---------------- gold path score + combine ----------------------------------
__global__ __launch_bounds__(256) void k_gold(const float* __restrict__ logits,
                                              const int* __restrict__ tgt,
                                              const float* __restrict__ trans,
                                              const float* __restrict__ logz,
                                              float* __restrict__ partial){
  int b = blockIdx.x, tid = threadIdx.x;
  float local = 0.f;
  for(int s=tid; s<S_LEN; s+=256){
    int ts = tgt[s*BATCH + b];
    local += logits[((size_t)s*BATCH + b)*NTAGS + ts];
    if(s > 0){
      int tp = tgt[(s-1)*BATCH + b];
      local += trans[tp*NTAGS + ts];
    }
  }
  __shared__ float red[4];
  for(int o=32;o>0;o>>=1) local += __shfl_down(local, o, 64);
  if((tid&63)==0) red[tid>>6] = local;
  __syncthreads();
  if(tid==0) partial[b] = logz[b] - (red[0]+red[1]+red[2]+red[3]);
}
__global__ __launch_bounds__(128) void k_final(const float* __restrict__ partial,
                                               float* __restrict__ out){
  int t = threadIdx.x;
  float v = partial[t];
  for(int o=32;o>0;o>>=1) v += __shfl_down(v, o, 64);
  __shared__ float r2[2];
  if((t&63)==0) r2[t>>6] = v;
  __syncthreads();
  if(t==0) out[0] = (r2[0]+r2[1]) * (1.0f/BATCH);
}

// ---------------- launcher ---------------------------------------------------
extern "C" void kernel_launch(void* const* d_in, const int* in_sizes, int n_in,
                              void* d_out, int out_size, void* d_ws, size_t ws_size,
                              hipStream_t stream){
  const int*   src   = (const int*)d_in[0];
  const int*   tgt   = (const int*)d_in[1];
  const float* emb   = (const float*)d_in[2];
  const float* Wih   = (const float*)d_in[3];
  const float* Whh   = (const float*)d_in[4];
  const float* bih   = (const float*)d_in[5];
  const float* bhh   = (const float*)d_in[6];
  const float* Wlin  = (const float*)d_in[7];
  const float* blin  = (const float*)d_in[8];
  const float* trans = (const float*)d_in[9];
  float* out = (float*)d_out;
  char* ws = (char*)d_ws;

  // workspace layout — total ~197.4 MB
  ushort_t* xA     = (ushort_t*)(ws + 0);              //  67,108,864
  ushort_t* xB     = (ushort_t*)(ws + 67108864);       //  67,108,864
  ushort_t* preF   = (ushort_t*)(ws + 134217728);      //  33,554,432 [CHUNK*B,1024]
  ushort_t* preB   = (ushort_t*)(ws + 167772160);      //  33,554,432
  ushort_t* WihB   = (ushort_t*)(ws + 201326592);      //   4,194,304
  uchar_t*  Wq8    = (uchar_t*) (ws + 205520896);      //   1,048,576 fp8 Whh
  ushort_t* WlinB  = (ushort_t*)(ws + 206569472);      //      32,768
  float*    bsum   = (float*)   (ws + 206602240);      //      16,384
  uchar_t*  hstate = (uchar_t*) (ws + 206618624);      //      65,536 fp8
  float*    cstate = (float*)   (ws + 206684160);      //     262,144
  float*    logz   = (float*)   (ws + 206946304);      //         512
  float*    partial= (float*)   (ws + 206946816);      //         512
  float*    logits = (float*)   (ws + 134217728);      // aliases preF (dead by then)

  // weight conversions
  k_cvt_bf16<<<dim3(8192),dim3(256),0,stream>>>(Wih,  WihB,  2*2*1024*512);
  k_cvt_fp8 <<<dim3(4096),dim3(256),0,stream>>>(Whh,  Wq8,   2*2*1024*256);
  k_cvt_bf16<<<dim3(64),  dim3(256),0,stream>>>(Wlin, WlinB, 32*512);
  k_biassum <<<dim3(16),  dim3(256),0,stream>>>(bih, bhh, bsum, 2*2*1024);

  // embedding
  k_embed<<<dim3(MROWS),dim3(64),0,stream>>>(src, emb, xA);

  for(int l=0;l<2;++l){
    const ushort_t* xin = l ? xB : xA;
    ushort_t*      xout = l ? xA : xB;
    // zero h (fp8) + c (f32) — contiguous
    hipMemsetAsync(hstate, 0, 65536 + 262144, stream);
    const uchar_t* WqL = Wq8 + (size_t)l*2*1024*HIDDEN;
    for(int cI=0;cI<S_LEN/CHUNK;++cI){
      int t0 = cI*CHUNK;
      // dir0 band: sequence rows [t0, t0+CHUNK)
      k_gemm_pre<<<dim3(16, CHUNK*BATCH/64),dim3(256),0,stream>>>(
          xin + (size_t)t0*BATCH*DMODEL,
          WihB + (size_t)(l*2+0)*1024*DMODEL,
          bsum + (l*2+0)*1024, preF, 1024, 1);
      // dir1 band: sequence rows [S-t0-CHUNK, S-t0)
      k_gemm_pre<<<dim3(16, CHUNK*BATCH/64),dim3(256),0,stream>>>(
          xin + (size_t)(S_LEN - t0 - CHUNK)*BATCH*DMODEL,
          WihB + (size_t)(l*2+1)*1024*DMODEL,
          bsum + (l*2+1)*1024, preB, 1024, 1);
      // per-batch scan over this chunk (both directions), all 256 CUs
      k_scan3<<<dim3(256),dim3(512),0,stream>>>(
          preF, preB, WqL, hstate, cstate, xout, t0);
    }
  }

  k_logits<<<dim3(MROWS/16),dim3(128),0,stream>>>(xA, WlinB, blin, logits);
  k_crf   <<<dim3(BATCH),dim3(64),0,stream>>>(logits, trans, logz);
  k_gold  <<<dim3(BATCH),dim3(256),0,stream>>>(logits, tgt, trans, logz, partial);
  k_final <<<dim3(1),dim3(128),0,stream>>>(partial, out);
}

// Round 2
// 2821.693 us; speedup vs baseline: 1.1763x; 1.0922x over previous
//
#include <hip/hip_runtime.h>
#include <math.h>

typedef __attribute__((ext_vector_type(8))) short short8;
typedef __attribute__((ext_vector_type(4))) float float4v;
typedef __attribute__((ext_vector_type(8))) int int8v;
typedef unsigned short ushort_t;
typedef unsigned char uchar_t;

#define S_LEN 512
#define BATCH 128
#define DMODEL 512
#define HIDDEN 256
#define NTAGS 32
#define MROWS (S_LEN*BATCH)
#define CHUNK 128                 // sequence steps per pre-band
#define EMB_SCALE 22.62741699796952f

__device__ __forceinline__ float bf2f(ushort_t u){
  union { unsigned int i; float f; } v; v.i = ((unsigned int)u)<<16; return v.f;
}
__device__ __forceinline__ ushort_t f2bf(float f){
  union { float f; unsigned int i; } v; v.f = f;
  unsigned int x = v.i;
  x += 0x7fffu + ((x>>16)&1u);
  return (ushort_t)(x>>16);
}
// float -> OCP e4m3fn, RNE, saturate to 448
__device__ __forceinline__ uchar_t f2fp8(float f){
  float a = fabsf(f);
  unsigned int s = (__float_as_uint(f) >> 24) & 0x80u;
  if (a >= 448.f) return (uchar_t)(s | 0x7Eu);
  if (a < 0.015625f){                         // subnormal: m = round(a*512)
    unsigned int q = (unsigned int)__float2int_rn(a * 512.0f);
    return (uchar_t)(s | q);
  }
  unsigned int x = __float_as_uint(a);
  x += 0x7FFFFu + ((x >> 20) & 1u);           // RNE into 3-bit mantissa
  int e = (int)((x >> 23) & 0xFFu) - 127;
  unsigned int m = (x >> 20) & 7u;
  if (e > 8) return (uchar_t)(s | 0x7Eu);
  return (uchar_t)(s | ((unsigned)(e + 7) << 3) | m);
}
__device__ __forceinline__ float sigm(float x){ return 1.0f/(1.0f+__expf(-x)); }
__device__ __forceinline__ float tanh_f(float x){ return 2.0f/(1.0f+__expf(-2.0f*x)) - 1.0f; }

#define MFMA(a,b,c) __builtin_amdgcn_mfma_f32_16x16x32_bf16(a,b,c,0,0,0)
// block-scaled MX fp8 MFMA, K=128, unit scales (e8m0 0x7F = 2^0)
#define MFMAMX(a,b,c) __builtin_amdgcn_mfma_scale_f32_16x16x128_f8f6f4( \
    a, b, c, 0, 0, 0, 0x7F7F7F7F, 0, 0x7F7F7F7F)

// ---------------- elementwise helpers ----------------
__global__ void k_cvt_bf16(const float* __restrict__ s, ushort_t* __restrict__ d, int n){
  int i = blockIdx.x*blockDim.x + threadIdx.x;
  if(i<n) d[i] = f2bf(s[i]);
}
__global__ void k_cvt_fp8(const float* __restrict__ s, uchar_t* __restrict__ d, int n){
  int i = blockIdx.x*blockDim.x + threadIdx.x;
  if(i<n) d[i] = f2fp8(s[i]);
}
__global__ void k_biassum(const float* __restrict__ a, const float* __restrict__ b,
                          float* __restrict__ o, int n){
  int i = blockIdx.x*blockDim.x + threadIdx.x;
  if(i<n) o[i] = a[i]+b[i];
}

// ---------------- embedding: x[s,b,:] = emb[src[s,b],:]*sqrt(D)  (bf16 out) ----
__global__ __launch_bounds__(64) void k_embed(const int* __restrict__ src,
                                              const float* __restrict__ emb,
                                              ushort_t* __restrict__ x){
  int row = blockIdx.x;            // 0..65535  (= s*BATCH+b)
  int t = threadIdx.x;             // 64 threads, 8 elems each
  int tok = src[row];
  const float4v* e = (const float4v*)(emb + (size_t)tok*DMODEL + t*8);
  float4v a = e[0], b = e[1];
  short8 o;
  o[0]=(short)f2bf(a[0]*EMB_SCALE); o[1]=(short)f2bf(a[1]*EMB_SCALE);
  o[2]=(short)f2bf(a[2]*EMB_SCALE); o[3]=(short)f2bf(a[3]*EMB_SCALE);
  o[4]=(short)f2bf(b[0]*EMB_SCALE); o[5]=(short)f2bf(b[1]*EMB_SCALE);
  o[6]=(short)f2bf(b[2]*EMB_SCALE); o[7]=(short)f2bf(b[3]*EMB_SCALE);
  *(short8*)(x + (size_t)row*DMODEL + t*8) = o;
}

// ---------------- band pre-GEMM: C[Mband,N] = A[Mband,512] @ W[N,512]^T + bias -
// perm!=0: write gate-interleaved layout col' = (unit<<2)|gate (unit=col&255,
// gate=col>>8) so the scan kernel reads 4 gates of one unit as one ushort4.
__global__ __launch_bounds__(256) void k_gemm_pre(const ushort_t* __restrict__ A,
                                                  const ushort_t* __restrict__ W,
                                                  const float* __restrict__ bias,
                                                  ushort_t* __restrict__ C, int N,
                                                  int perm){
  __shared__ __align__(16) ushort_t As[64][40];   // +8 pad: 2-way banks only
  __shared__ __align__(16) ushort_t Bs[64][40];
  const int K = 512;
  int bn = blockIdx.x;             // N/64 tiles
  int bm = blockIdx.y;             // Mband/64 tiles
  int tid = threadIdx.x;
  int lane = tid & 63, wave = tid >> 6;
  int wm = wave >> 1, wn = wave & 1;        // 32x32 quadrant per wave
  int srow = tid >> 2, scg = tid & 3;       // staging: row, 8-elem group
  float4v acc[2][2] = {};
  const ushort_t* Ag = A + ((size_t)(bm*64 + srow))*K + scg*8;
  const ushort_t* Wg = W + ((size_t)(bn*64 + srow))*K + scg*8;
  int r = lane & 15;
  int kq = (lane >> 4) * 8;
  for(int kt=0; kt<K/32; ++kt){
    *(short8*)&As[srow][scg*8] = *(const short8*)(Ag + kt*32);
    *(short8*)&Bs[srow][scg*8] = *(const short8*)(Wg + kt*32);
    __syncthreads();
    short8 a0 = *(const short8*)&As[wm*32 +      r][kq];
    short8 a1 = *(const short8*)&As[wm*32 + 16 + r][kq];
    short8 b0 = *(const short8*)&Bs[wn*32 +      r][kq];
    short8 b1 = *(const short8*)&Bs[wn*32 + 16 + r][kq];
    acc[0][0] = MFMA(a0,b0,acc[0][0]);
    acc[0][1] = MFMA(a0,b1,acc[0][1]);
    acc[1][0] = MFMA(a1,b0,acc[1][0]);
    acc[1][1] = MFMA(a1,b1,acc[1][1]);
    __syncthreads();
  }
  int r0 = (lane>>4)*4, cc = lane & 15;
  for(int mt=0;mt<2;++mt) for(int nt=0;nt<2;++nt){
    int col = bn*64 + wn*32 + nt*16 + cc;
    float bv = bias[col];
    int colp = perm ? (((col & 255) << 2) | (col >> 8)) : col;
    for(int j=0;j<4;++j){
      int row = bm*64 + wm*32 + mt*16 + r0 + j;
      C[(size_t)row*N + colp] = f2bf(acc[mt][nt][j] + bv);
    }
  }
}

// ---------------- per-batch bidirectional LSTM scan over one CHUNK ------------
// grid = 256 blocks x 512 threads: bid = d*128 + b. ONE batch element per
// block -> every CU busy; recurrence is batch-independent so no cross-block
// traffic. Per step each block multiplies full Whh[1024x256] by h[b].
// MX-scaled fp8 MFMA (16x16x128, unit scales): per wave 16 MFMA/step
// (4 gates x 2 uh x 2 K-tiles) vs 64 with 16x16x32 — per-CU matrix-pipe
// time ~1100 cy vs ~2050 cy on the serial critical path.
// Wave w owns units [w*32,+32). A-frag: lane l = row (l&15), k=(l>>4)*32+[0,32)
// — one MX block per lane; only hbuf row 0 is live (rows 1..15 zeroed once).
// C/D is shape-determined: row 0 = lanes 0-15, reg 0 (same as 16x16x32).
__global__ __launch_bounds__(512,1) void k_scan3(
    const ushort_t* __restrict__ preF,   // [CHUNK*B][1024] gate-interleaved dir0
    const ushort_t* __restrict__ preB,   // same, dir1 band (band rows = seq high->low)
    const uchar_t* __restrict__ Wq,      // [2,1024,256] fp8 (this layer)
    uchar_t* __restrict__ hstate,        // [2,128,256] fp8 carry between chunks
    float* __restrict__ cstate,          // [2,128,256] f32
    ushort_t* __restrict__ xout,         // [S*B,512] bf16
    int t0){
  __shared__ __align__(16) uchar_t hbuf[2][16][272];  // 8704 B; 16B-aligned rows
  int bid = blockIdx.x;
  int d = bid >> 7, b = bid & 127;
  int tid = threadIdx.x;
  int w = tid >> 6, lane = tid & 63;
  int lo = lane & 15, hi = lane >> 4;
  int u0 = w*32;                           // wave's unit base [0,256)

  // zero hbuf, then load initial h row
  for(int i = tid*4; i < 2*16*272; i += 512*4)
    *(unsigned int*)((uchar_t*)hbuf + i) = 0u;
  __syncthreads();
  if(tid < 64)
    *(unsigned int*)&hbuf[0][0][tid*4] =
      *(const unsigned int*)(hstate + ((size_t)d*BATCH + b)*HIDDEN + tid*4);

  // fp8 weights -> 128 VGPRs/lane: wq[g][uh][kt], 32 B per lane per frag
  // B-frag: lane l = col (l&15), k = (l>>4)*32 + [0,32)
  int8v wq[4][2][2];
  const uchar_t* Wd = Wq + (size_t)d*1024*HIDDEN;
  #pragma unroll
  for(int g=0; g<4; ++g)
    #pragma unroll
    for(int uh=0; uh<2; ++uh)
      #pragma unroll
      for(int kt=0; kt<2; ++kt)
        wq[g][uh][kt] = *(const int8v*)
          (Wd + (size_t)(g*256 + u0 + uh*16 + lo)*HIDDEN + kt*128 + hi*32);

  float c[2];
  #pragma unroll
  for(int uh=0; uh<2; ++uh)
    c[uh] = cstate[((size_t)d*BATCH + b)*HIDDEN + u0 + uh*16 + lo];

  const ushort_t* pp = (d ? preB : preF) + (size_t)b*1024;
  ushort4 pc[2], pn[2];
  {
    int br = d ? (CHUNK-1) : 0;
    if(hi==0){
      #pragma unroll
      for(int uh=0; uh<2; ++uh)
        pc[uh] = *(const ushort4*)(pp + (size_t)br*BATCH*1024 + (u0+uh*16+lo)*4);
    }
  }
  __syncthreads();

  for(int sb=0; sb<CHUNK; ++sb){
    int p = sb & 1;
    // prefetch next step's pre (independent of recurrence)
    int sb2 = (sb+1 < CHUNK) ? sb+1 : sb;
    int br2 = d ? (CHUNK-1-sb2) : sb2;
    if(hi==0){
      #pragma unroll
      for(int uh=0; uh<2; ++uh)
        pn[uh] = *(const ushort4*)(pp + (size_t)br2*BATCH*1024 + (u0+uh*16+lo)*4);
    }

    float4v acc[4][2] = {};
    int8v ha0 = *(const int8v*)&hbuf[p][lo][hi*32];          // k 0..127
    int8v ha1 = *(const int8v*)&hbuf[p][lo][128 + hi*32];    // k 128..255
    #pragma unroll
    for(int g=0; g<4; ++g){
      acc[g][0] = MFMAMX(ha0, wq[g][0][0], acc[g][0]);
      acc[g][1] = MFMAMX(ha0, wq[g][1][0], acc[g][1]);
      acc[g][0] = MFMAMX(ha1, wq[g][0][1], acc[g][0]);
      acc[g][1] = MFMAMX(ha1, wq[g][1][1], acc[g][1]);
    }

    int s = t0 + sb;
    int s_eff = d ? (S_LEN-1-s) : s;
    if(hi==0){
      #pragma unroll
      for(int uh=0; uh<2; ++uh){
        float gi = acc[0][uh][0] + bf2f(pc[uh].x);
        float gf = acc[1][uh][0] + bf2f(pc[uh].y);
        float gg = acc[2][uh][0] + bf2f(pc[uh].z);
        float go = acc[3][uh][0] + bf2f(pc[uh].w);
        float cn = sigm(gf)*c[uh] + sigm(gi)*tanh_f(gg);
        float hn = sigm(go)*tanh_f(cn);
        c[uh] = cn;
        int u = u0 + uh*16 + lo;
        hbuf[p^1][0][u] = f2fp8(hn);
        xout[((size_t)s_eff*BATCH + b)*DMODEL + d*HIDDEN + u] = f2bf(hn);
      }
    }
    __syncthreads();
    #pragma unroll
    for(int uh=0; uh<2; ++uh) pc[uh] = pn[uh];
  }

  // write back h (CHUNK even -> final h in hbuf[0]) and c
  if(tid < 64)
    *(unsigned int*)(hstate + ((size_t)d*BATCH + b)*HIDDEN + tid*4) =
      *(const unsigned int*)&hbuf[0][0][tid*4];
  if(hi==0){
    #pragma unroll
    for(int uh=0; uh<2; ++uh)
      cstate[((size_t)d*BATCH + b)*HIDDEN + u0 + uh*16 + lo] = c[uh];
  }
}

// ---------------- logits: [M,32] = x[M,512] @ W_lin^T + b_lin  (f32 out) ------
__global__ __launch_bounds__(128) void k_logits(const ushort_t* __restrict__ x,
                                                const ushort_t* __restrict__ Wl,
                                                const float* __restrict__ bl,
                                                float* __restrict__ logits){
  __shared__ ushort_t xr[16][512];
  __shared__ ushort_t wl[32][520];   // pad -> 4-way max
  int tid = threadIdx.x;
  int base = blockIdx.x * 16;
  for(int i=tid; i<16*64; i+=128){
    int row = i >> 6, cg = i & 63;
    *(short8*)&xr[row][cg*8] = *(const short8*)(x + (size_t)(base+row)*DMODEL + cg*8);
  }
  for(int i=tid; i<32*64; i+=128){
    int row = i >> 6, cg = i & 63;
    *(short8*)&wl[row][cg*8] = *(const short8*)(Wl + (size_t)row*DMODEL + cg*8);
  }
  __syncthreads();
  int rr = tid >> 5, t = tid & 31;
  float bv = bl[t];
  for(int p=0;p<4;++p){
    int row = p*4 + rr;
    float sum = 0.f;
    for(int k8=0;k8<64;++k8){
      short8 xv = *(const short8*)&xr[row][k8*8];
      short8 wv = *(const short8*)&wl[t][k8*8];
      #pragma unroll
      for(int j=0;j<8;++j)
        sum += bf2f((ushort_t)xv[j]) * bf2f((ushort_t)wv[j]);
    }
    logits[((size_t)(base+row))*NTAGS + t] = sum + bv;
  }
}

// ---------------- CRF partition: per-batch alpha recurrence ------------------
// Scaled exp-domain formulation: a[t] = exp(alpha[t] - M).  Per step:
//   a_new[t] = (sum_j a[j]*expT[j][t]) * exp(e[t])
// expT held in 32 VGPRs/lane (computed once); only ONE transcendental per
// step on the critical path, and its input (emission) is prefetched 2 steps
// ahead.  All sums are of positive terms (no cancellation).  Exact power-of-2
// rescale keeps a in range; triggered by a cheap wave-uniform __any/__all
// check.  Lanes 32-63 mirror lanes 0-31 (uniform wave ops, no divergence).
__global__ __launch_bounds__(64) void k_crf(const float* __restrict__ logits,
                                            const float* __restrict__ trans,
                                            float* __restrict__ logz){
  __shared__ __align__(16) float sh[32];
  int b = blockIdx.x, tid = threadIdx.x;
  int t = tid & 31;                       // lanes 32-63 mirror 0-31

  // per-lane column of exp(T): eT[j] = exp(trans[j][t])
  float eT[32];
  #pragma unroll
  for(int j=0;j<32;++j) eT[j] = __expf(trans[j*NTAGS + t]);

  // init: alpha0 = logits[0,b,:]; a = exp(alpha0 - m0), M = m0
  float al0 = logits[(size_t)b*NTAGS + t];
  float m0 = al0;
  #pragma unroll
  for(int o=1;o<32;o<<=1) m0 = fmaxf(m0, __shfl_xor(m0, o));
  float Mf = m0;
  float a = __expf(al0 - m0);

  const size_t stp = (size_t)BATCH*NTAGS;
  const float* ebase = logits + (size_t)b*NTAGS + t;
  float eCur = ebase[stp*1];              // emission for step 1
  float eNxt = ebase[stp*2];              // emission for step 2
  const float* eptr = ebase + stp*3;      // prefetch pointer (step i+2 at i=1)

  for(int i=1;i<S_LEN;++i){
    float expE = __expf(eCur);            // input was prefetched 2 steps ago
    if(tid < 32) sh[t] = a;
    __syncthreads();
    // prefetch emission for step i+2 (independent of recurrence)
    float eP = 0.f;
    if(i+2 < S_LEN) eP = *eptr;
    eptr += stp;
    // s_t = sum_j a[j] * expT[j][t] — 4 independent FMA chains
    float s0=0.f, s1=0.f, s2=0.f, s3=0.f;
    const float4v* s4 = (const float4v*)sh;
    #pragma unroll
    for(int q=0;q<8;++q){
      float4v v = s4[q];
      s0 = __fmaf_rn(v[0], eT[q*4+0], s0);
      s1 = __fmaf_rn(v[1], eT[q*4+1], s1);
      s2 = __fmaf_rn(v[2], eT[q*4+2], s2);
      s3 = __fmaf_rn(v[3], eT[q*4+3], s3);
    }
    a = ((s0+s1)+(s2+s3)) * expE;
    eCur = eNxt; eNxt = eP;
    // exact power-of-2 renorm when out of range (wave-uniform branch)
    if(__any(a > 1.1529215e18f) || __all(a < 9.0949470e-13f)){   // 2^60 / 2^-40
      float m = a;
      #pragma unroll
      for(int o=1;o<32;o<<=1) m = fmaxf(m, __shfl_xor(m, o));
      int e2 = (int)((__float_as_uint(m)>>23)&255u) - 127;
      float scl = __uint_as_float((unsigned)(127 - e2) << 23);   // 2^-e2 exact
      a *= scl;
      Mf += (float)e2 * 0.69314718055994531f;
    }
    __syncthreads();
  }
  // logz = M + log(sum_t a)
  float sum = a;
  #pragma unroll
  for(int o=1;o<32;o<<=1) sum += __shfl_xor(sum, o);
  if(tid==0) logz[b] = Mf + __logf(sum);
}

// ---------------- gold path score + combine ----------------------------------
__global__ __launch_bounds__(256) void k_gold(const float* __restrict__ logits,
                                              const int* __restrict__ tgt,
                                              const float* __restrict__ trans,
                                              const float* __restrict__ logz,
                                              float* __restrict__ partial){
  int b = blockIdx.x, tid = threadIdx.x;
  float local = 0.f;
  for(int s=tid; s<S_LEN; s+=256){
    int ts = tgt[s*BATCH + b];
    local += logits[((size_t)s*BATCH + b)*NTAGS + ts];
    if(s > 0){
      int tp = tgt[(s-1)*BATCH + b];
      local += trans[tp*NTAGS + ts];
    }
  }
  __shared__ float red[4];
  for(int o=32;o>0;o>>=1) local += __shfl_down(local, o, 64);
  if((tid&63)==0) red[tid>>6] = local;
  __syncthreads();
  if(tid==0) partial[b] = logz[b] - (red[0]+red[1]+red[2]+red[3]);
}
__global__ __launch_bounds__(128) void k_final(const float* __restrict__ partial,
                                               float* __restrict__ out){
  int t = threadIdx.x;
  float v = partial[t];
  for(int o=32;o>0;o>>=1) v += __shfl_down(v, o, 64);
  __shared__ float r2[2];
  if((t&63)==0) r2[t>>6] = v;
  __syncthreads();
  if(t==0) out[0] = (r2[0]+r2[1]) * (1.0f/BATCH);
}

// ---------------- launcher ---------------------------------------------------
extern "C" void kernel_launch(void* const* d_in, const int* in_sizes, int n_in,
                              void* d_out, int out_size, void* d_ws, size_t ws_size,
                              hipStream_t stream){
  const int*   src   = (const int*)d_in[0];
  const int*   tgt   = (const int*)d_in[1];
  const float* emb   = (const float*)d_in[2];
  const float* Wih   = (const float*)d_in[3];
  const float* Whh   = (const float*)d_in[4];
  const float* bih   = (const float*)d_in[5];
  const float* bhh   = (const float*)d_in[6];
  const float* Wlin  = (const float*)d_in[7];
  const float* blin  = (const float*)d_in[8];
  const float* trans = (const float*)d_in[9];
  float* out = (float*)d_out;
  char* ws = (char*)d_ws;

  // workspace layout — total ~197.4 MB
  ushort_t* xA     = (ushort_t*)(ws + 0);              //  67,108,864
  ushort_t* xB     = (ushort_t*)(ws + 67108864);       //  67,108,864
  ushort_t* preF   = (ushort_t*)(ws + 134217728);      //  33,554,432 [CHUNK*B,1024]
  ushort_t* preB   = (ushort_t*)(ws + 167772160);      //  33,554,432
  ushort_t* WihB   = (ushort_t*)(ws + 201326592);      //   4,194,304
  uchar_t*  Wq8    = (uchar_t*) (ws + 205520896);      //   1,048,576 fp8 Whh
  ushort_t* WlinB  = (ushort_t*)(ws + 206569472);      //      32,768
  float*    bsum   = (float*)   (ws + 206602240);      //      16,384
  uchar_t*  hstate = (uchar_t*) (ws + 206618624);      //      65,536 fp8
  float*    cstate = (float*)   (ws + 206684160);      //     262,144
  float*    logz   = (float*)   (ws + 206946304);      //         512
  float*    partial= (float*)   (ws + 206946816);      //         512
  float*    logits = (float*)   (ws + 134217728);      // aliases preF (dead by then)

  // weight conversions
  k_cvt_bf16<<<dim3(8192),dim3(256),0,stream>>>(Wih,  WihB,  2*2*1024*512);
  k_cvt_fp8 <<<dim3(4096),dim3(256),0,stream>>>(Whh,  Wq8,   2*2*1024*256);
  k_cvt_bf16<<<dim3(64),  dim3(256),0,stream>>>(Wlin, WlinB, 32*512);
  k_biassum <<<dim3(16),  dim3(256),0,stream>>>(bih, bhh, bsum, 2*2*1024);

  // embedding
  k_embed<<<dim3(MROWS),dim3(64),0,stream>>>(src, emb, xA);

  for(int l=0;l<2;++l){
    const ushort_t* xin = l ? xB : xA;
    ushort_t*      xout = l ? xA : xB;
    // zero h (fp8) + c (f32) — contiguous
    hipMemsetAsync(hstate, 0, 65536 + 262144, stream);
    const uchar_t* WqL = Wq8 + (size_t)l*2*1024*HIDDEN;
    for(int cI=0;cI<S_LEN/CHUNK;++cI){
      int t0 = cI*CHUNK;
      // dir0 band: sequence rows [t0, t0+CHUNK)
      k_gemm_pre<<<dim3(16, CHUNK*BATCH/64),dim3(256),0,stream>>>(
          xin + (size_t)t0*BATCH*DMODEL,
          WihB + (size_t)(l*2+0)*1024*DMODEL,
          bsum + (l*2+0)*1024, preF, 1024, 1);
      // dir1 band: sequence rows [S-t0-CHUNK, S-t0)
      k_gemm_pre<<<dim3(16, CHUNK*BATCH/64),dim3(256),0,stream>>>(
          xin + (size_t)(S_LEN - t0 - CHUNK)*BATCH*DMODEL,
          WihB + (size_t)(l*2+1)*1024*DMODEL,
          bsum + (l*2+1)*1024, preB, 1024, 1);
      // per-batch scan over this chunk (both directions), all 256 CUs
      k_scan3<<<dim3(256),dim3(512),0,stream>>>(
          preF, preB, WqL, hstate, cstate, xout, t0);
    }
  }

  k_logits<<<dim3(MROWS/16),dim3(128),0,stream>>>(xA, WlinB, blin, logits);
  k_crf   <<<dim3(BATCH),dim3(64),0,stream>>>(logits, trans, logz);
  k_gold  <<<dim3(BATCH),dim3(256),0,stream>>>(logits, tgt, trans, logz, partial);
  k_final <<<dim3(1),dim3(128),0,stream>>>(partial, out);
}